// Round 7
// baseline (118.263 us; speedup 1.0000x reference)
//
#include <hip/hip_runtime.h>

#define BB 4
#define NN 16384
#define MM 8192      // N/2
#define FD 64
#define CHUNK 256    // candidates staged per LDS tile (1 per thread)
#define QPT 4        // queries per thread (register-blocked)
#define TPB 256      // threads per block
#define QPB (TPB * QPT)   // 1024 queries per block

// d_out float offsets (outputs concatenated flat in return order)
#define OUT0 0              // valid_pc   (4,8192,3)  = 98304
#define OUT1 98304          // valid_feats(4,8192,64) = 2097152
#define OUT2 2195456        // n_idx      (4,8192)    = 32768
#define OUT3 2228224        // rnds       (1,16384)   = 16384

struct Partial { float m1, m2; int i1, i2; };  // 16B

// Reference fp32 chain (verified absmax=0): rounded squares, sequential adds.
__device__ __forceinline__ float sumsq3_rn(float x, float y, float z) {
  return __fadd_rn(__fadd_rn(__fmul_rn(x, x), __fmul_rn(y, y)), __fmul_rn(z, z));
}

__global__ __launch_bounds__(256) void gather_kernel(
    const float* __restrict__ pc, const float* __restrict__ feats,
    const int* __restrict__ perm, float* __restrict__ out) {
  int idx = blockIdx.x * 256 + threadIdx.x;
  const int F4_TOT = BB * MM * FD / 4;   // 524288 float4 of feats
  const int PTS    = BB * MM;            // 32768 valid points (pc)
  if (idx < F4_TOT) {
    int f4 = idx & 15;                   // float4 within row
    int r  = (idx >> 4) & (MM - 1);
    int b  = idx >> 17;                  // / (MM*16)
    int vi = perm[r];
    const float4* src = (const float4*)(feats + ((b * NN + vi) << 6));
    float4* dst = (float4*)(out + OUT1) + idx;
    *dst = src[f4];
  } else if (idx < F4_TOT + PTS) {
    int k = idx - F4_TOT;
    int r = k & (MM - 1);
    int b = k >> 13;
    int vi = perm[r];
    const float* src = pc + (b * NN + vi) * 3;
    float* dst = out + OUT0 + k * 3;
    dst[0] = src[0]; dst[1] = src[1]; dst[2] = src[2];
  } else if (idx < F4_TOT + PTS + NN) {
    int k = idx - F4_TOT - PTS;
    out[OUT3 + k] = (float)perm[k];
  }
}

// Each block: QPB queries (QPT/thread in registers) x (MM/nchunk) candidates.
// Tile stores (2px, 2py, 2pz, p2): scaling by 2 commutes with rounding, so
// cross2 = fma(qz,2pz, fma(qy,2py, rn(qx*2px))) == 2*cross bit-exactly.
__global__ __launch_bounds__(256) void knn_kernel(
    const float* __restrict__ pc, const int* __restrict__ perm,
    Partial* __restrict__ part, float* __restrict__ out, int nchunk) {
  #pragma clang fp contract(off)
  int blk = blockIdx.x;
  int c  = blk % nchunk;          // chunk id
  int qb = blk / nchunk;          // query-block id
  int q0 = qb * QPB + threadIdx.x;   // first of QPT strided queries
  int b  = q0 >> 13;              // QPB divides MM -> whole block same batch

  float qx[QPT], qy[QPT], qz[QPT], q2[QPT], m1[QPT], m2[QPT];
  int   i1[QPT], i2[QPT];
  #pragma unroll
  for (int s = 0; s < QPT; ++s) {
    int q = q0 + s * TPB;
    int j = q & (MM - 1);
    int qi = perm[MM + j];
    const float* qp = pc + (b * NN + qi) * 3;
    qx[s] = qp[0]; qy[s] = qp[1]; qz[s] = qp[2];
    q2[s] = sumsq3_rn(qx[s], qy[s], qz[s]);
    m1[s] = 3.4e38f; m2[s] = 3.4e38f; i1[s] = 0; i2[s] = 0;
  }

  __shared__ float4 tile[CHUNK];   // (2x, 2y, 2z, p2)  4 KB

  int span = MM / nchunk;
  int begin = c * span, end = begin + span;

  for (int t0 = begin; t0 < end; t0 += CHUNK) {
    __syncthreads();
    {
      int k = threadIdx.x;                 // CHUNK == TPB: one each
      int vi = perm[t0 + k];
      const float* pp = pc + (b * NN + vi) * 3;
      float px = pp[0], py = pp[1], pz = pp[2];
      tile[k] = make_float4(px + px, py + py, pz + pz, sumsq3_rn(px, py, pz));
    }
    __syncthreads();
    #pragma unroll 4
    for (int k = 0; k < CHUNK; ++k) {
      float4 t = tile[k];
      int idx = t0 + k;
      #pragma unroll
      for (int s = 0; s < QPT; ++s) {
        // cross2 = 2*cross, bit-exact (see note above)
        float cross2 = __fmaf_rn(qz[s], t.z,
                       __fmaf_rn(qy[s], t.y, __fmul_rn(qx[s], t.x)));
        float d2 = __fadd_rn(__fsub_rn(q2[s], cross2), t.w);
        bool lt1 = d2 < m1[s];
        bool lt2 = d2 < m2[s];
        // indices first (read old m1/i1), then values
        i2[s] = lt1 ? i1[s] : (lt2 ? idx : i2[s]);
        i1[s] = lt1 ? idx : i1[s];
        // m2' = median{d2, m1, m2}; m1' = min  — identical to verified recurrence
        m2[s] = __builtin_amdgcn_fmed3f(d2, m1[s], m2[s]);
        m1[s] = fminf(d2, m1[s]);
      }
    }
  }

  #pragma unroll
  for (int s = 0; s < QPT; ++s) {
    int q = q0 + s * TPB;
    if (part != nullptr) {
      Partial pr; pr.m1 = m1[s]; pr.m2 = m2[s]; pr.i1 = i1[s]; pr.i2 = i2[s];
      part[q * nchunk + c] = pr;
    } else {
      out[OUT2 + q] = (float)i2[s];
    }
  }
}

__global__ __launch_bounds__(256) void knn_merge_kernel(
    const Partial* __restrict__ part, float* __restrict__ out, int nchunk) {
  int q = blockIdx.x * 256 + threadIdx.x;   // 0..B*M-1
  float m1 = 3.4e38f, m2 = 3.4e38f;
  int i1 = 0, i2 = 0;
  for (int c = 0; c < nchunk; ++c) {
    Partial p = part[q * nchunk + c];
    // ascending chunk order = ascending candidate-index ranges, so strict <
    // preserves top_k's stable lowest-index-first tie semantics.
    if (p.m1 < m1)      { m2 = m1; i2 = i1; m1 = p.m1; i1 = p.i1; }
    else if (p.m1 < m2) { m2 = p.m1; i2 = p.i1; }
    if (p.m2 < m1)      { m2 = m1; i2 = i1; m1 = p.m2; i1 = p.i2; }
    else if (p.m2 < m2) { m2 = p.m2; i2 = p.i2; }
  }
  out[OUT2 + q] = (float)i2;
}

extern "C" void kernel_launch(void* const* d_in, const int* in_sizes, int n_in,
                              void* d_out, int out_size, void* d_ws, size_t ws_size,
                              hipStream_t stream) {
  const float* pc    = (const float*)d_in[0];
  const float* feats = (const float*)d_in[1];
  const int*   perm  = (const int*)d_in[2];
  float* out = (float*)d_out;

  // Gather domains: 524288 float4 + 32768 pts + 16384 rnds = 573440 -> 2240 blocks
  gather_kernel<<<2240, 256, 0, stream>>>(pc, feats, perm, out);

  // Largest chunk split whose partials fit in d_ws.
  // qblocks = 32, so nchunk=32 -> 1024 blocks (4/CU, 16 waves/CU).
  int nchunk = 1;
  if      (ws_size >= (size_t)BB * MM * 32 * sizeof(Partial)) nchunk = 32;  // 16.8 MB
  else if (ws_size >= (size_t)BB * MM * 16 * sizeof(Partial)) nchunk = 16;
  else if (ws_size >= (size_t)BB * MM * 8  * sizeof(Partial)) nchunk = 8;
  else if (ws_size >= (size_t)BB * MM * 4  * sizeof(Partial)) nchunk = 4;
  else if (ws_size >= (size_t)BB * MM * 2  * sizeof(Partial)) nchunk = 2;

  int qblocks = BB * MM / QPB;   // 32
  if (nchunk > 1) {
    Partial* part = (Partial*)d_ws;
    knn_kernel<<<qblocks * nchunk, TPB, 0, stream>>>(pc, perm, part, out, nchunk);
    knn_merge_kernel<<<BB * MM / 256, 256, 0, stream>>>(part, out, nchunk);
  } else {
    knn_kernel<<<qblocks, TPB, 0, stream>>>(pc, perm, nullptr, out, 1);
  }
}

// Round 8
// 104.828 us; speedup vs baseline: 1.1282x; 1.1282x over previous
//
#include <hip/hip_runtime.h>

#define BB 4
#define NN 16384
#define MM 8192      // N/2
#define FD 64
#define CHUNK 256    // candidates staged per LDS tile (1 per thread)
#define QPT 2        // queries per thread (register-blocked)
#define TPB 256      // threads per block
#define QPB (TPB * QPT)   // 512 queries per block

// d_out float offsets (outputs concatenated flat in return order)
#define OUT0 0              // valid_pc   (4,8192,3)  = 98304
#define OUT1 98304          // valid_feats(4,8192,64) = 2097152
#define OUT2 2195456        // n_idx      (4,8192)    = 32768
#define OUT3 2228224        // rnds       (1,16384)   = 16384

struct Partial { float m1, m2; int i1, i2; };  // 16B

// Reference fp32 chain (verified absmax=0): rounded squares, sequential adds.
__device__ __forceinline__ float sumsq3_rn(float x, float y, float z) {
  return __fadd_rn(__fadd_rn(__fmul_rn(x, x), __fmul_rn(y, y)), __fmul_rn(z, z));
}

__global__ __launch_bounds__(256) void gather_kernel(
    const float* __restrict__ pc, const float* __restrict__ feats,
    const int* __restrict__ perm, float* __restrict__ out) {
  int idx = blockIdx.x * 256 + threadIdx.x;
  const int F4_TOT = BB * MM * FD / 4;   // 524288 float4 of feats
  const int PTS    = BB * MM;            // 32768 valid points (pc)
  if (idx < F4_TOT) {
    int f4 = idx & 15;                   // float4 within row
    int r  = (idx >> 4) & (MM - 1);
    int b  = idx >> 17;                  // / (MM*16)
    int vi = perm[r];
    const float4* src = (const float4*)(feats + ((b * NN + vi) << 6));
    float4* dst = (float4*)(out + OUT1) + idx;
    *dst = src[f4];
  } else if (idx < F4_TOT + PTS) {
    int k = idx - F4_TOT;
    int r = k & (MM - 1);
    int b = k >> 13;
    int vi = perm[r];
    const float* src = pc + (b * NN + vi) * 3;
    float* dst = out + OUT0 + k * 3;
    dst[0] = src[0]; dst[1] = src[1]; dst[2] = src[2];
  } else if (idx < F4_TOT + PTS + NN) {
    int k = idx - F4_TOT - PTS;
    out[OUT3 + k] = (float)perm[k];
  }
}

// Each block: QPB queries (QPT/thread in registers) x (MM/nchunk) candidates.
// Tile stores (2px, 2py, 2pz, p2): scaling by 2 commutes with rounding, so
// cross2 = fma(qz,2pz, fma(qy,2py, rn(qx*2px))) == 2*cross bit-exactly
// (validated on HW in round 7: absmax 0).
__global__ __launch_bounds__(256) void knn_kernel(
    const float* __restrict__ pc, const int* __restrict__ perm,
    Partial* __restrict__ part, float* __restrict__ out, int nchunk) {
  #pragma clang fp contract(off)
  int blk = blockIdx.x;
  int c  = blk % nchunk;          // chunk id
  int qb = blk / nchunk;          // query-block id
  int q0 = qb * QPB + threadIdx.x;   // first of QPT strided queries
  int b  = q0 >> 13;              // QPB divides MM -> whole block same batch

  float qx[QPT], qy[QPT], qz[QPT], q2[QPT], m1[QPT], m2[QPT];
  int   i1[QPT], i2[QPT];
  #pragma unroll
  for (int s = 0; s < QPT; ++s) {
    int q = q0 + s * TPB;
    int j = q & (MM - 1);
    int qi = perm[MM + j];
    const float* qp = pc + (b * NN + qi) * 3;
    qx[s] = qp[0]; qy[s] = qp[1]; qz[s] = qp[2];
    q2[s] = sumsq3_rn(qx[s], qy[s], qz[s]);
    m1[s] = 3.4e38f; m2[s] = 3.4e38f; i1[s] = 0; i2[s] = 0;
  }

  __shared__ float4 tile[CHUNK];   // (2x, 2y, 2z, p2)  4 KB

  int span = MM / nchunk;
  int begin = c * span, end = begin + span;

  for (int t0 = begin; t0 < end; t0 += CHUNK) {
    __syncthreads();
    {
      int k = threadIdx.x;                 // CHUNK == TPB: one each
      int vi = perm[t0 + k];
      const float* pp = pc + (b * NN + vi) * 3;
      float px = pp[0], py = pp[1], pz = pp[2];
      tile[k] = make_float4(px + px, py + py, pz + pz, sumsq3_rn(px, py, pz));
    }
    __syncthreads();
    #pragma unroll 8
    for (int k = 0; k < CHUNK; ++k) {
      float4 t = tile[k];
      int idx = t0 + k;
      #pragma unroll
      for (int s = 0; s < QPT; ++s) {
        // cross2 = 2*cross, bit-exact (see note above)
        float cross2 = __fmaf_rn(qz[s], t.z,
                       __fmaf_rn(qy[s], t.y, __fmul_rn(qx[s], t.x)));
        float d2 = __fadd_rn(__fsub_rn(q2[s], cross2), t.w);
        bool lt1 = d2 < m1[s];
        bool lt2 = d2 < m2[s];
        // indices first (read old m1/i1), then values
        i2[s] = lt1 ? i1[s] : (lt2 ? idx : i2[s]);
        i1[s] = lt1 ? idx : i1[s];
        // m2' = median{d2, m1, m2}; m1' = min  — identical to verified recurrence
        m2[s] = __builtin_amdgcn_fmed3f(d2, m1[s], m2[s]);
        m1[s] = fminf(d2, m1[s]);
      }
    }
  }

  #pragma unroll
  for (int s = 0; s < QPT; ++s) {
    int q = q0 + s * TPB;
    if (part != nullptr) {
      Partial pr; pr.m1 = m1[s]; pr.m2 = m2[s]; pr.i1 = i1[s]; pr.i2 = i2[s];
      part[q * nchunk + c] = pr;
    } else {
      out[OUT2 + q] = (float)i2[s];
    }
  }
}

__global__ __launch_bounds__(256) void knn_merge_kernel(
    const Partial* __restrict__ part, float* __restrict__ out, int nchunk) {
  int q = blockIdx.x * 256 + threadIdx.x;   // 0..B*M-1
  float m1 = 3.4e38f, m2 = 3.4e38f;
  int i1 = 0, i2 = 0;
  for (int c = 0; c < nchunk; ++c) {
    Partial p = part[q * nchunk + c];
    // ascending chunk order = ascending candidate-index ranges, so strict <
    // preserves top_k's stable lowest-index-first tie semantics.
    if (p.m1 < m1)      { m2 = m1; i2 = i1; m1 = p.m1; i1 = p.i1; }
    else if (p.m1 < m2) { m2 = p.m1; i2 = p.i1; }
    if (p.m2 < m1)      { m2 = m1; i2 = i1; m1 = p.m2; i1 = p.i2; }
    else if (p.m2 < m2) { m2 = p.m2; i2 = p.i2; }
  }
  out[OUT2 + q] = (float)i2;
}

extern "C" void kernel_launch(void* const* d_in, const int* in_sizes, int n_in,
                              void* d_out, int out_size, void* d_ws, size_t ws_size,
                              hipStream_t stream) {
  const float* pc    = (const float*)d_in[0];
  const float* feats = (const float*)d_in[1];
  const int*   perm  = (const int*)d_in[2];
  float* out = (float*)d_out;

  // Gather domains: 524288 float4 + 32768 pts + 16384 rnds = 573440 -> 2240 blocks
  gather_kernel<<<2240, 256, 0, stream>>>(pc, feats, perm, out);

  // Largest chunk split whose partials fit in d_ws.
  // qblocks = 64, so nchunk=32 -> 2048 blocks (8/CU, 32 waves/CU) — r6's best.
  int nchunk = 1;
  if      (ws_size >= (size_t)BB * MM * 32 * sizeof(Partial)) nchunk = 32;  // 16.8 MB
  else if (ws_size >= (size_t)BB * MM * 16 * sizeof(Partial)) nchunk = 16;
  else if (ws_size >= (size_t)BB * MM * 8  * sizeof(Partial)) nchunk = 8;
  else if (ws_size >= (size_t)BB * MM * 4  * sizeof(Partial)) nchunk = 4;
  else if (ws_size >= (size_t)BB * MM * 2  * sizeof(Partial)) nchunk = 2;

  int qblocks = BB * MM / QPB;   // 64
  if (nchunk > 1) {
    Partial* part = (Partial*)d_ws;
    knn_kernel<<<qblocks * nchunk, TPB, 0, stream>>>(pc, perm, part, out, nchunk);
    knn_merge_kernel<<<BB * MM / 256, 256, 0, stream>>>(part, out, nchunk);
  } else {
    knn_kernel<<<qblocks, TPB, 0, stream>>>(pc, perm, nullptr, out, 1);
  }
}

// Round 9
// 104.238 us; speedup vs baseline: 1.1346x; 1.0057x over previous
//
#include <hip/hip_runtime.h>

#define BB 4
#define NN 16384
#define MM 8192      // N/2
#define FD 64
#define QPT 2        // queries per thread (register-blocked)
#define TPB 256      // threads per block
#define QPB (TPB * QPT)   // 512 queries per block

// d_out float offsets (outputs concatenated flat in return order)
#define OUT0 0              // valid_pc   (4,8192,3)  = 98304
#define OUT1 98304          // valid_feats(4,8192,64) = 2097152
#define OUT2 2195456        // n_idx      (4,8192)    = 32768
#define OUT3 2228224        // rnds       (1,16384)   = 16384

#define CAND_BYTES ((size_t)BB * MM * 16)   // 512 KB: float4 (2x,2y,2z,p2)

struct Partial { float m1, m2; int i1, i2; };  // 16B

// Reference fp32 chain (verified absmax=0): rounded squares, sequential adds.
__device__ __forceinline__ float sumsq3_rn(float x, float y, float z) {
  return __fadd_rn(__fadd_rn(__fmul_rn(x, x), __fmul_rn(y, y)), __fmul_rn(z, z));
}

__global__ __launch_bounds__(256) void gather_kernel(
    const float* __restrict__ pc, const float* __restrict__ feats,
    const int* __restrict__ perm, float* __restrict__ out,
    float4* __restrict__ cand) {
  int idx = blockIdx.x * 256 + threadIdx.x;
  const int F4_TOT = BB * MM * FD / 4;   // 524288 float4 of feats
  const int PTS    = BB * MM;            // 32768 valid points (pc)
  if (idx < F4_TOT) {
    int f4 = idx & 15;                   // float4 within row
    int r  = (idx >> 4) & (MM - 1);
    int b  = idx >> 17;                  // / (MM*16)
    int vi = perm[r];
    const float4* src = (const float4*)(feats + ((b * NN + vi) << 6));
    float4* dst = (float4*)(out + OUT1) + idx;
    *dst = src[f4];
  } else if (idx < F4_TOT + PTS) {
    int k = idx - F4_TOT;                // k == b*MM + r == cand index
    int r = k & (MM - 1);
    int b = k >> 13;
    int vi = perm[r];
    const float* src = pc + (b * NN + vi) * 3;
    float px = src[0], py = src[1], pz = src[2];
    float* dst = out + OUT0 + k * 3;
    dst[0] = px; dst[1] = py; dst[2] = pz;
    // pre-doubled coords + p2 (2x commutes with rounding — HW-verified r7)
    cand[k] = make_float4(px + px, py + py, pz + pz, sumsq3_rn(px, py, pz));
  } else if (idx < F4_TOT + PTS + NN) {
    int k = idx - F4_TOT - PTS;
    out[OUT3 + k] = (float)perm[k];
  }
}

// Each block: QPB queries (QPT/thread in registers) x (MM/nchunk) candidates
// streamed from the global cand array via WAVE-UNIFORM addresses (b, k derive
// from blockIdx only) -> compiler scalarizes to s_load; candidate components
// enter the VALU ops as sgpr operands. No LDS, no barriers.
__global__ __launch_bounds__(256) void knn_kernel(
    const float* __restrict__ pc, const int* __restrict__ perm,
    const float4* __restrict__ cand,
    Partial* __restrict__ part, float* __restrict__ out, int nchunk) {
  #pragma clang fp contract(off)
  int blk = blockIdx.x;
  int c  = blk % nchunk;          // chunk id
  int qb = blk / nchunk;          // query-block id
  int q0 = qb * QPB + threadIdx.x;   // first of QPT strided queries
  int b  = qb >> 4;               // == (qb*QPB)>>13, blockIdx-only -> uniform

  float qx[QPT], qy[QPT], qz[QPT], q2[QPT], m1[QPT], m2[QPT];
  int   i1[QPT], i2[QPT];
  #pragma unroll
  for (int s = 0; s < QPT; ++s) {
    int q = q0 + s * TPB;
    int j = q & (MM - 1);
    int qi = perm[MM + j];
    const float* qp = pc + (b * NN + qi) * 3;
    qx[s] = qp[0]; qy[s] = qp[1]; qz[s] = qp[2];
    q2[s] = sumsq3_rn(qx[s], qy[s], qz[s]);
    m1[s] = 3.4e38f; m2[s] = 3.4e38f; i1[s] = 0; i2[s] = 0;
  }

  const float4* __restrict__ cb = cand + b * MM;
  int span = MM / nchunk;
  int begin = c * span, end = begin + span;

  #pragma unroll 4
  for (int k = begin; k < end; ++k) {
    float4 t = cb[k];               // uniform addr -> s_load (sgpr operands)
    #pragma unroll
    for (int s = 0; s < QPT; ++s) {
      // cross2 = 2*cross bit-exactly (pre-doubled coords, HW-verified r7)
      float cross2 = __fmaf_rn(qz[s], t.z,
                     __fmaf_rn(qy[s], t.y, __fmul_rn(qx[s], t.x)));
      float d2 = __fadd_rn(__fsub_rn(q2[s], cross2), t.w);
      bool lt1 = d2 < m1[s];
      bool lt2 = d2 < m2[s];
      // indices first (read old i1), then values
      i2[s] = lt1 ? i1[s] : (lt2 ? k : i2[s]);
      i1[s] = lt1 ? k : i1[s];
      // m2' = median{d2,m1,m2}; m1' = min — identical to verified recurrence
      m2[s] = __builtin_amdgcn_fmed3f(d2, m1[s], m2[s]);
      m1[s] = fminf(d2, m1[s]);
    }
  }

  #pragma unroll
  for (int s = 0; s < QPT; ++s) {
    int q = q0 + s * TPB;
    if (part != nullptr) {
      Partial pr; pr.m1 = m1[s]; pr.m2 = m2[s]; pr.i1 = i1[s]; pr.i2 = i2[s];
      part[q * nchunk + c] = pr;
    } else {
      out[OUT2 + q] = (float)i2[s];
    }
  }
}

__global__ __launch_bounds__(256) void knn_merge_kernel(
    const Partial* __restrict__ part, float* __restrict__ out, int nchunk) {
  int q = blockIdx.x * 256 + threadIdx.x;   // 0..B*M-1
  float m1 = 3.4e38f, m2 = 3.4e38f;
  int i1 = 0, i2 = 0;
  for (int c = 0; c < nchunk; ++c) {
    Partial p = part[q * nchunk + c];
    // ascending chunk order = ascending candidate-index ranges, so strict <
    // preserves top_k's stable lowest-index-first tie semantics.
    if (p.m1 < m1)      { m2 = m1; i2 = i1; m1 = p.m1; i1 = p.i1; }
    else if (p.m1 < m2) { m2 = p.m1; i2 = p.i1; }
    if (p.m2 < m1)      { m2 = m1; i2 = i1; m1 = p.m2; i1 = p.i2; }
    else if (p.m2 < m2) { m2 = p.m2; i2 = p.i2; }
  }
  out[OUT2 + q] = (float)i2;
}

extern "C" void kernel_launch(void* const* d_in, const int* in_sizes, int n_in,
                              void* d_out, int out_size, void* d_ws, size_t ws_size,
                              hipStream_t stream) {
  const float* pc    = (const float*)d_in[0];
  const float* feats = (const float*)d_in[1];
  const int*   perm  = (const int*)d_in[2];
  float* out = (float*)d_out;

  float4* cand = (float4*)d_ws;                          // 512 KB
  char*   rest = (char*)d_ws + CAND_BYTES;
  size_t  avail = ws_size > CAND_BYTES ? ws_size - CAND_BYTES : 0;

  // Gather (+ cand prep, free: reuses the valid_pc loads): 2240 blocks
  gather_kernel<<<2240, 256, 0, stream>>>(pc, feats, perm, out, cand);

  // Largest chunk split whose partials fit after cand.
  // qblocks = 64 -> nchunk=32 gives 2048 blocks (8/CU, 32 waves/CU) — r6 best.
  int nchunk = 1;
  if      (avail >= (size_t)BB * MM * 32 * sizeof(Partial)) nchunk = 32;  // 16.8 MB
  else if (avail >= (size_t)BB * MM * 16 * sizeof(Partial)) nchunk = 16;
  else if (avail >= (size_t)BB * MM * 8  * sizeof(Partial)) nchunk = 8;
  else if (avail >= (size_t)BB * MM * 4  * sizeof(Partial)) nchunk = 4;
  else if (avail >= (size_t)BB * MM * 2  * sizeof(Partial)) nchunk = 2;

  int qblocks = BB * MM / QPB;   // 64
  if (nchunk > 1) {
    Partial* part = (Partial*)rest;
    knn_kernel<<<qblocks * nchunk, TPB, 0, stream>>>(pc, perm, cand, part, out, nchunk);
    knn_merge_kernel<<<BB * MM / 256, 256, 0, stream>>>(part, out, nchunk);
  } else {
    knn_kernel<<<qblocks, TPB, 0, stream>>>(pc, perm, cand, nullptr, out, 1);
  }
}

// Round 10
// 75.628 us; speedup vs baseline: 1.5637x; 1.3783x over previous
//
#include <hip/hip_runtime.h>

#define BB 4
#define NN 16384
#define MM 8192      // N/2
#define FD 64
#define CHUNK 256    // candidates staged per LDS tile (1 per thread)
#define QPT 2        // queries per thread (register-blocked)
#define TPB 256      // threads per block
#define QPB (TPB * QPT)   // 512 queries per block

// d_out float offsets (outputs concatenated flat in return order)
#define OUT0 0              // valid_pc   (4,8192,3)  = 98304
#define OUT1 98304          // valid_feats(4,8192,64) = 2097152
#define OUT2 2195456        // n_idx      (4,8192)    = 32768
#define OUT3 2228224        // rnds       (1,16384)   = 16384

#define CAND_BYTES ((size_t)BB * MM * 16)   // 512 KB: float4 (2x,2y,2z,p2)

struct Partial { double m1, m2; };  // 16B packed keys

// Reference fp32 chain (verified absmax=0): rounded squares, sequential adds.
__device__ __forceinline__ float sumsq3_rn(float x, float y, float z) {
  return __fadd_rn(__fadd_rn(__fmul_rn(x, x), __fmul_rn(y, y)), __fmul_rn(z, z));
}

// Packed key: hi word = f32 bits of d2, lo word = candidate index.
// f64 ordering == (f32 d2 compare, then lower-index-first) for all finite d2.
__device__ __forceinline__ double mkkey(float d2, int k) {
  return __hiloint2double(__float_as_int(d2), k);
}
#define KEY_INIT __hiloint2double(0x7F800000, 0x7FFFFFFF)   // +inf d2 sentinel

__global__ __launch_bounds__(256) void gather_kernel(
    const float* __restrict__ pc, const float* __restrict__ feats,
    const int* __restrict__ perm, float* __restrict__ out,
    float4* __restrict__ cand) {
  int idx = blockIdx.x * 256 + threadIdx.x;
  const int F4_TOT = BB * MM * FD / 4;   // 524288 float4 of feats
  const int PTS    = BB * MM;            // 32768 valid points (pc)
  if (idx < F4_TOT) {
    int f4 = idx & 15;                   // float4 within row
    int r  = (idx >> 4) & (MM - 1);
    int b  = idx >> 17;                  // / (MM*16)
    int vi = perm[r];
    const float4* src = (const float4*)(feats + ((b * NN + vi) << 6));
    float4* dst = (float4*)(out + OUT1) + idx;
    *dst = src[f4];
  } else if (idx < F4_TOT + PTS) {
    int k = idx - F4_TOT;                // k == b*MM + r == cand index
    int r = k & (MM - 1);
    int b = k >> 13;
    int vi = perm[r];
    const float* src = pc + (b * NN + vi) * 3;
    float px = src[0], py = src[1], pz = src[2];
    float* dst = out + OUT0 + k * 3;
    dst[0] = px; dst[1] = py; dst[2] = pz;
    // pre-doubled coords + p2 (2x commutes with rounding — HW-verified r7)
    cand[k] = make_float4(px + px, py + py, pz + pz, sumsq3_rn(px, py, pz));
  } else if (idx < F4_TOT + PTS + NN) {
    int k = idx - F4_TOT - PTS;
    out[OUT3 + k] = (float)perm[k];
  }
}

// Each block: QPB queries (QPT/thread) x span candidates via LDS broadcast.
// Top-2 tracked as packed f64 keys: 3 f64 min/max ops, no compares/cndmasks.
__global__ __launch_bounds__(256) void knn_kernel(
    const float* __restrict__ pc, const int* __restrict__ perm,
    const float4* __restrict__ cand,
    Partial* __restrict__ part, float* __restrict__ out, int nchunk) {
  #pragma clang fp contract(off)
  int blk = blockIdx.x;
  int c  = blk % nchunk;          // chunk id
  int qb = blk / nchunk;          // query-block id
  int q0 = qb * QPB + threadIdx.x;   // first of QPT strided queries
  int b  = qb >> 4;               // blockIdx-only -> uniform

  float qx[QPT], qy[QPT], qz[QPT], q2[QPT];
  double m1[QPT], m2[QPT];
  #pragma unroll
  for (int s = 0; s < QPT; ++s) {
    int q = q0 + s * TPB;
    int j = q & (MM - 1);
    int qi = perm[MM + j];
    const float* qp = pc + (b * NN + qi) * 3;
    qx[s] = qp[0]; qy[s] = qp[1]; qz[s] = qp[2];
    q2[s] = sumsq3_rn(qx[s], qy[s], qz[s]);
    m1[s] = KEY_INIT; m2[s] = KEY_INIT;
  }

  __shared__ float4 tile[CHUNK];   // (2x, 2y, 2z, p2)  4 KB

  int span = MM / nchunk;
  int begin = c * span, end = begin + span;

  for (int t0 = begin; t0 < end; t0 += CHUNK) {
    __syncthreads();
    tile[threadIdx.x] = cand[b * MM + t0 + threadIdx.x];  // coalesced, L2-hot
    __syncthreads();
    #pragma unroll 8
    for (int k = 0; k < CHUNK; ++k) {
      float4 t = tile[k];
      int idx = t0 + k;
      #pragma unroll
      for (int s = 0; s < QPT; ++s) {
        // cross2 = 2*cross bit-exactly (pre-doubled coords, HW-verified r7)
        float cross2 = __fmaf_rn(qz[s], t.z,
                       __fmaf_rn(qy[s], t.y, __fmul_rn(qx[s], t.x)));
        float d2 = __fadd_rn(__fsub_rn(q2[s], cross2), t.w);
        double key = mkkey(d2, idx);
        // top-2 via total-order keys: m2' = min(max(key,m1), m2); m1' = min
        m2[s] = fmin(fmax(key, m1[s]), m2[s]);
        m1[s] = fmin(key, m1[s]);
      }
    }
  }

  #pragma unroll
  for (int s = 0; s < QPT; ++s) {
    int q = q0 + s * TPB;
    if (part != nullptr) {
      Partial pr; pr.m1 = m1[s]; pr.m2 = m2[s];
      part[q * nchunk + c] = pr;
    } else {
      out[OUT2 + q] = (float)__double2loint(m2[s]);
    }
  }
}

__global__ __launch_bounds__(256) void knn_merge_kernel(
    const Partial* __restrict__ part, float* __restrict__ out, int nchunk) {
  int q = blockIdx.x * 256 + threadIdx.x;   // 0..B*M-1
  double m1 = KEY_INIT, m2 = KEY_INIT;
  for (int c = 0; c < nchunk; ++c) {
    Partial p = part[q * nchunk + c];
    // key insertion is order-independent (keys are totally ordered)
    m2 = fmin(fmax(p.m1, m1), m2);
    m1 = fmin(p.m1, m1);
    m2 = fmin(fmax(p.m2, m1), m2);
    m1 = fmin(p.m2, m1);
  }
  out[OUT2 + q] = (float)__double2loint(m2);
}

extern "C" void kernel_launch(void* const* d_in, const int* in_sizes, int n_in,
                              void* d_out, int out_size, void* d_ws, size_t ws_size,
                              hipStream_t stream) {
  const float* pc    = (const float*)d_in[0];
  const float* feats = (const float*)d_in[1];
  const int*   perm  = (const int*)d_in[2];
  float* out = (float*)d_out;

  float4* cand = (float4*)d_ws;                          // 512 KB
  char*   rest = (char*)d_ws + CAND_BYTES;
  size_t  avail = ws_size > CAND_BYTES ? ws_size - CAND_BYTES : 0;

  // Gather (+ cand prep): 2240 blocks
  gather_kernel<<<2240, 256, 0, stream>>>(pc, feats, perm, out, cand);

  // Largest chunk split whose partials fit after cand.
  // qblocks = 64 -> nchunk=32 gives 2048 blocks (8/CU) — r6's best shape.
  int nchunk = 1;
  if      (avail >= (size_t)BB * MM * 32 * sizeof(Partial)) nchunk = 32;  // 16.8 MB
  else if (avail >= (size_t)BB * MM * 16 * sizeof(Partial)) nchunk = 16;
  else if (avail >= (size_t)BB * MM * 8  * sizeof(Partial)) nchunk = 8;
  else if (avail >= (size_t)BB * MM * 4  * sizeof(Partial)) nchunk = 4;
  else if (avail >= (size_t)BB * MM * 2  * sizeof(Partial)) nchunk = 2;

  int qblocks = BB * MM / QPB;   // 64
  if (nchunk > 1) {
    Partial* part = (Partial*)rest;
    knn_kernel<<<qblocks * nchunk, TPB, 0, stream>>>(pc, perm, cand, part, out, nchunk);
    knn_merge_kernel<<<BB * MM / 256, 256, 0, stream>>>(part, out, nchunk);
  } else {
    knn_kernel<<<qblocks, TPB, 0, stream>>>(pc, perm, cand, nullptr, out, 1);
  }
}